// Round 7
// baseline (255.748 us; speedup 1.0000x reference)
//
#include <hip/hip_runtime.h>

// out[n,c,h,w] = sum_{5x5 in-bounds taps} exp(-0.5*||xyz_nbr - xyz_ctr||^2)
//                * mask_nbr * softmax[n,c,nbr]
// OOB taps have weight forced to 0, so loads only need SAFE (clamped)
// addresses; clamped-slot garbage is multiplied by 0.0f.
//
// R11 = R9's barrier-free mapping, un-strangled.
// Evidence: R5-R10 two-phase LDS+barrier variants all 113-141us with
// VALUBusy pinned <=22% (occupancy 2x'd in R7, batched in R8, phase-1
// de-latencied in R10 -> -3us only). R9 (barrier-free, 1px x 20ch/lane)
// hit 150us ONLY because __launch_bounds__(256,5) pinned 44 VGPR ->
// w[25] resident left ~4 loads in flight. R11 fixes exactly that:
//  - plain __launch_bounds__(256): allocator lands ~90-130 VGPR, no spill
//    (R5/R8/R10 precedent); min-waves bounds are banned (R6/R7 spill).
//  - vector windows: per (c,r) one 4B-aligned float4 @ px-2 + scalar @
//    px+2 (10 loads/channel vs 25). 4B-aligned f4 proven in R8-R10.
//  - edge lanes: WAVE-UNIFORM branch (only first wave of chunk 0 / last
//    wave of chunk 7) -> R9 clamped-scalar path, no divergence.
// No LDS, no __syncthreads, independent waves, #pragma unroll 2 over the
// 20-channel loop -> ~20 independent loads in flight per wave.
// 1D grid ONLY (2D gridDim.y broke harness graph replay in R3).

#define H_DIM 64
#define W_DIM 2048
#define C_DIM 20
#define N_DIM 8
#define HW (H_DIM * W_DIM)
#define BLOCK 256

__global__ __launch_bounds__(BLOCK) void lcx_kernel(
    const float* __restrict__ xyz,
    const float* __restrict__ sm,
    const int*  __restrict__ mask,
    float* __restrict__ out)
{
    const int b  = blockIdx.x;            // 4096 blocks: 8 wchunks x 64 h x 8 n
    const int wc = b & 7;
    const int h  = (b >> 3) & (H_DIM - 1);
    const int n  = b >> 9;
    const int px = (wc << 8) + threadIdx.x;   // this lane's pixel column

    const float* xyzn  = xyz  + n * 3 * HW;
    const int*   maskn = mask + n * HW;

    // ---------------- Phase A: 25 weights in registers ----------------
    float w[25];
    {
        const int ctr = h * W_DIM + px;
        const float cx = xyzn[ctr];
        const float cy = xyzn[HW + ctr];
        const float cz = xyzn[2 * HW + ctr];
        const bool interior = (px >= 2) && (px <= W_DIM - 3);

        #pragma unroll
        for (int r = 0; r < 5; ++r) {
            const int hi = h + r - 2;
            if ((unsigned)hi >= (unsigned)H_DIM) {
                #pragma unroll
                for (int dj = 0; dj < 5; ++dj) w[r * 5 + dj] = 0.0f;
            } else {
                const int rb = hi * W_DIM;
                if (interior) {
                    const int o = rb + px - 2;
                    const float4 xv = *(const float4*)(xyzn + o);
                    const float  xs = xyzn[o + 4];
                    const float4 yv = *(const float4*)(xyzn + HW + o);
                    const float  ys = xyzn[HW + o + 4];
                    const float4 zv = *(const float4*)(xyzn + 2 * HW + o);
                    const float  zs = xyzn[2 * HW + o + 4];
                    const int4   mv = *(const int4*)(maskn + o);
                    const int    ms = maskn[o + 4];
                    const float nx[5] = {xv.x, xv.y, xv.z, xv.w, xs};
                    const float ny[5] = {yv.x, yv.y, yv.z, yv.w, ys};
                    const float nz[5] = {zv.x, zv.y, zv.z, zv.w, zs};
                    const int   nm[5] = {mv.x, mv.y, mv.z, mv.w, ms};
                    #pragma unroll
                    for (int dj = 0; dj < 5; ++dj) {
                        const float dx = nx[dj] - cx;
                        const float dy = ny[dj] - cy;
                        const float dz = nz[dj] - cz;
                        const float d2 = fmaf(dx, dx, fmaf(dy, dy, dz * dz));
                        w[r * 5 + dj] = (nm[dj] != 0) ? __expf(-0.5f * d2) : 0.0f;
                    }
                } else {
                    #pragma unroll
                    for (int dj = 0; dj < 5; ++dj) {
                        const int col = px + dj - 2;
                        const bool cok = ((unsigned)col < (unsigned)W_DIM);
                        const int cc  = cok ? col : (col < 0 ? 0 : W_DIM - 1);
                        const int o   = rb + cc;
                        const float dx = xyzn[o] - cx;
                        const float dy = xyzn[HW + o] - cy;
                        const float dz = xyzn[2 * HW + o] - cz;
                        const float d2 = fmaf(dx, dx, fmaf(dy, dy, dz * dz));
                        const bool ok = cok && (maskn[o] != 0);
                        w[r * 5 + dj] = ok ? __expf(-0.5f * d2) : 0.0f;
                    }
                }
            }
        }
    }

    // ---------------- Phase B: 20 channels, 25 taps each ----------------
    // clamped row bases: wave-uniform (h per-block) -> SGPRs
    int rbc[5];
    #pragma unroll
    for (int r = 0; r < 5; ++r) {
        const int hi = h + r - 2;
        rbc[r] = ((hi < 0) ? 0 : (hi >= H_DIM ? H_DIM - 1 : hi)) * W_DIM;
    }

    const float* smn  = sm  + n * C_DIM * HW;
    float*       outn = out + n * C_DIM * HW;
    const int octr = h * W_DIM + px;

    // wave-uniform edge test: wave 0 of chunk 0 holds px<2; wave 3 of
    // chunk 7 holds px>2045; every other wave is fully interior.
    const int wave = threadIdx.x >> 6;
    const bool edgewave = (wc == 0 && wave == 0) || (wc == 7 && wave == 3);

    if (!edgewave) {
        // interior: window [px-2 .. px+2] = f4 @ px-2 (4B-aligned OK) + scalar
        #pragma unroll 2
        for (int c = 0; c < C_DIM; ++c) {
            const float* pc = smn + c * HW + px;
            float a0 = 0.0f, a1 = 0.0f;
            #pragma unroll
            for (int r = 0; r < 5; ++r) {
                const float* p = pc + rbc[r];
                const float4 f  = *(const float4*)(p - 2);
                const float  s4 = p[2];
                a0 = fmaf(w[r * 5 + 0], f.x, a0);
                a1 = fmaf(w[r * 5 + 1], f.y, a1);
                a0 = fmaf(w[r * 5 + 2], f.z, a0);
                a1 = fmaf(w[r * 5 + 3], f.w, a1);
                a0 = fmaf(w[r * 5 + 4], s4,  a0);
            }
            outn[c * HW + octr] = a0 + a1;
        }
    } else {
        // edge: clamped scalar loads; weights at clamped cols are 0
        int coff[5];
        #pragma unroll
        for (int dj = 0; dj < 5; ++dj) {
            const int col = px + dj - 2;
            coff[dj] = (col < 0) ? 0 : (col > W_DIM - 1 ? W_DIM - 1 : col);
        }
        #pragma unroll 2
        for (int c = 0; c < C_DIM; ++c) {
            const float* pc = smn + c * HW;
            float a0 = 0.0f, a1 = 0.0f;
            #pragma unroll
            for (int r = 0; r < 5; ++r) {
                const float* pr = pc + rbc[r];
                a0 = fmaf(w[r * 5 + 0], pr[coff[0]], a0);
                a1 = fmaf(w[r * 5 + 1], pr[coff[1]], a1);
                a0 = fmaf(w[r * 5 + 2], pr[coff[2]], a0);
                a1 = fmaf(w[r * 5 + 3], pr[coff[3]], a1);
                a0 = fmaf(w[r * 5 + 4], pr[coff[4]], a0);
            }
            outn[c * HW + octr] = a0 + a1;
        }
    }
}

extern "C" void kernel_launch(void* const* d_in, const int* in_sizes, int n_in,
                              void* d_out, int out_size, void* d_ws, size_t ws_size,
                              hipStream_t stream)
{
    const float* xyz  = (const float*)d_in[0];
    const float* sm   = (const float*)d_in[1];
    const int*   mask = (const int*)d_in[2];
    float*       out  = (float*)d_out;

    const int grid = 8 * H_DIM * N_DIM;   // 4096 blocks, 1D ONLY

    lcx_kernel<<<grid, BLOCK, 0, stream>>>(xyz, sm, mask, out);
}

// Round 8
// 214.096 us; speedup vs baseline: 1.1945x; 1.1945x over previous
//
#include <hip/hip_runtime.h>

// out[n,c,h,w] = sum_{5x5 in-bounds taps} exp(-0.5*||xyz_nbr - xyz_ctr||^2)
//                * mask_nbr * softmax[n,c,nbr]
// OOB taps have weight forced to 0, so staged/loaded slots at clamped
// addresses may hold garbage; they are always multiplied by 0.0f.
//
// R12: LDS-fed compute + h-row reuse. Evidence R5-R11: every structure
// whose FMAs consume GLOBAL loads pins at 113-150us with VALUBusy 13-22%
// and HBM 15% -- occupancy (18->46%) and ILP restructuring both null.
// The untouched pipe is LDS (conflict 0 everywhere). R12 tiles 4 h-rows x
// 64 px x 20 ch per block and stages the sm halo ONCE into LDS (the 5x
// h-overlap every prior kernel re-fetched from global), then runs R5's
// proven f2/f4/f2 + b128-weight phase 2 entirely out of LDS.
//   LDS: sm_s 20x8x72 (46.1KB) + w_s 4x25x64 (25.6KB) + xyz_s 3x8x72
//   (6.9KB, mask folded as 1e30 -> d2=inf -> expf=0, R10-proven) = 78.6KB
//   (>64KB OK on gfx950; 8-phase GEMM example uses 128KB). 2 blocks/CU.
//   Stride 72 floats: b128 reads spread uniformly, 8 dwords/bank = min.
// Phase order: stage xyz -> sync -> {stage sm (12 indep f4 loads/thread,
// overlaps weight math) + compute weights from xyz_s} -> sync -> phase 2.
// Plain __launch_bounds__ (R6/R7: min-waves caps spill catastrophically).
// 1D grid ONLY (2D gridDim.y broke harness graph replay in R3).

#define H_DIM 64
#define W_DIM 2048
#define C_DIM 20
#define N_DIM 8
#define HW (H_DIM * W_DIM)
#define BLOCK 256
#define HT 4             // output h-rows per block
#define PX 64            // output pixels per block
#define RS 8             // staged rows = HT + 4
#define CS 72            // staged cols = PX + 8
#define NGX 18           // float4 groups per staged row

__global__ __launch_bounds__(BLOCK) void lcx_kernel(
    const float* __restrict__ xyz,
    const float* __restrict__ sm,
    const int*  __restrict__ mask,
    float* __restrict__ out)
{
    __shared__ float sm_s[C_DIM][RS][CS];   // 46.08 KB
    __shared__ float w_s[HT][25][PX];       // 25.6 KB
    __shared__ float xyz_s[3][RS][CS];      // 6.91 KB, mask folded into x

    const int b  = blockIdx.x;              // 4096: 32 pxc x 16 htile x 8 n
    const int pc = b & 31;
    const int ht = (b >> 5) & 15;
    const int n  = b >> 9;
    const int w0 = pc << 6;
    const int h0 = ht << 2;
    const int t  = threadIdx.x;

    const float* xyzn  = xyz  + n * 3 * HW;
    const int*   maskn = mask + n * HW;
    const float* smn   = sm   + n * C_DIM * HW;
    float*       outn  = out  + n * C_DIM * HW;

    // center coords for the weight phase (thread = (whh, wpl)); from
    // GLOBAL and NOT mask-folded (center's own mask only zeroes its tap
    // via the folded neighbor value).
    const int whh = t >> 6;                 // wave-uniform
    const int wpl = t & 63;
    const int ctr = (h0 + whh) * W_DIM + w0 + wpl;
    const float cx = xyzn[ctr];
    const float cy = xyzn[HW + ctr];
    const float cz = xyzn[2 * HW + ctr];

    // ---------- Phase 0: stage xyz halo (mask folded into x) ----------
    // jobs: 3 comp x 8 rows x 18 groups = 432 float4
    #pragma unroll
    for (int it = 0; it < 2; ++it) {
        const int j = t + (it << 8);
        if (j < 3 * RS * NGX) {
            const int grp  = j % NGX;
            const int rem  = j / NGX;       // comp*8 + row
            const int row  = rem & 7;
            const int comp = rem >> 3;
            const int hi   = h0 - 2 + row;
            const int hic  = (hi < 0) ? 0 : (hi > H_DIM - 1 ? H_DIM - 1 : hi);
            int gc = w0 - 4 + (grp << 2);
            gc = (gc < 0) ? 0 : (gc > W_DIM - 4 ? W_DIM - 4 : gc);
            const int o = hic * W_DIM + gc;
            float4 v = *(const float4*)(xyzn + comp * HW + o);
            if (comp == 0) {                // fold mask into x
                const int4 m = *(const int4*)(maskn + o);
                v.x = m.x ? v.x : 1e30f;
                v.y = m.y ? v.y : 1e30f;
                v.z = m.z ? v.z : 1e30f;
                v.w = m.w ? v.w : 1e30f;
            }
            *(float4*)&xyz_s[comp][row][grp << 2] = v;
        }
    }
    __syncthreads();

    // ---- Phase 1a: stage sm halo (independent loads, overlap weights) ----
    // jobs: 20c x 8 rows x 18 groups = 2880 float4
    #pragma unroll
    for (int it = 0; it < 12; ++it) {
        const int j = t + (it << 8);
        if (j < C_DIM * RS * NGX) {
            const int grp = j % NGX;
            const int rem = j / NGX;        // c*8 + row
            const int row = rem & 7;
            const int c   = rem >> 3;
            const int hi  = h0 - 2 + row;
            const int hic = (hi < 0) ? 0 : (hi > H_DIM - 1 ? H_DIM - 1 : hi);
            int gc = w0 - 4 + (grp << 2);
            gc = (gc < 0) ? 0 : (gc > W_DIM - 4 ? W_DIM - 4 : gc);
            *(float4*)&sm_s[c][row][grp << 2] =
                *(const float4*)(smn + c * HW + hic * W_DIM + gc);
        }
    }

    // ---------- Phase 1b: weights from xyz_s -> w_s ----------
    // thread = (whh = h-row 0..3, wpl = pixel 0..63)
    #pragma unroll
    for (int rt = 0; rt < 5; ++rt) {
        const int row  = whh + rt;          // xyz_s row for hi = h0+whh+rt-2
        const bool rok = ((unsigned)(h0 + whh + rt - 2) < (unsigned)H_DIM);
        float w5[5];
        #pragma unroll
        for (int dj = 0; dj < 5; ++dj) {
            const int cs   = wpl + dj + 2;  // staged col for px+dj-2
            const bool cok = ((unsigned)(w0 + wpl + dj - 2) < (unsigned)W_DIM);
            const float dx = xyz_s[0][row][cs] - cx;  // 1e30 if masked
            const float dy = xyz_s[1][row][cs] - cy;
            const float dz = xyz_s[2][row][cs] - cz;
            const float d2 = fmaf(dx, dx, fmaf(dy, dy, dz * dz));
            w5[dj] = (rok && cok) ? __expf(-0.5f * d2) : 0.0f;
        }
        #pragma unroll
        for (int dj = 0; dj < 5; ++dj)
            w_s[whh][rt * 5 + dj][wpl] = w5[dj];
    }
    __syncthreads();

    // ---------- Phase 2: 4 px x 5 ch per thread, ALL operands from LDS ----------
    const int cg = t >> 6;                  // channel group, wave-uniform
    const int hh = (t >> 4) & 3;            // output h-row within tile
    const int pq = t & 15;                  // pixel quad
    const int cb = pq << 2;                 // col base within PX

    float4 acc[5];
    #pragma unroll
    for (int c = 0; c < 5; ++c) acc[c] = make_float4(0.f, 0.f, 0.f, 0.f);

    #pragma unroll
    for (int rt = 0; rt < 5; ++rt) {
        const int row = hh + rt;            // sm_s row

        float4 wt[5];                       // aligned b128, bank-uniform
        #pragma unroll
        for (int dj = 0; dj < 5; ++dj)
            wt[dj] = *(const float4*)&w_s[hh][rt * 5 + dj][cb];

        #pragma unroll
        for (int c = 0; c < 5; ++c) {
            const float* pr = &sm_s[cg * 5 + c][row][0];
            const float2 f0 = *(const float2*)(pr + cb + 2);   // 8B-aligned
            const float4 f1 = *(const float4*)(pr + cb + 4);   // 16B-aligned
            const float2 f2 = *(const float2*)(pr + cb + 8);   // 8B-aligned
            float fs[8];
            fs[0]=f0.x; fs[1]=f0.y; fs[2]=f1.x; fs[3]=f1.y;
            fs[4]=f1.z; fs[5]=f1.w; fs[6]=f2.x; fs[7]=f2.y;

            #pragma unroll
            for (int dj = 0; dj < 5; ++dj) {
                acc[c].x = fmaf(wt[dj].x, fs[0 + dj], acc[c].x);
                acc[c].y = fmaf(wt[dj].y, fs[1 + dj], acc[c].y);
                acc[c].z = fmaf(wt[dj].z, fs[2 + dj], acc[c].z);
                acc[c].w = fmaf(wt[dj].w, fs[3 + dj], acc[c].w);
            }
        }
    }

    const int ob = (h0 + hh) * W_DIM + w0 + cb;
    #pragma unroll
    for (int c = 0; c < 5; ++c)
        *(float4*)(outn + (cg * 5 + c) * HW + ob) = acc[c];
}

extern "C" void kernel_launch(void* const* d_in, const int* in_sizes, int n_in,
                              void* d_out, int out_size, void* d_ws, size_t ws_size,
                              hipStream_t stream)
{
    const float* xyz  = (const float*)d_in[0];
    const float* sm   = (const float*)d_in[1];
    const int*   mask = (const int*)d_in[2];
    float*       out  = (float*)d_out;

    const int grid = 32 * 16 * N_DIM;     // 4096 blocks, 1D ONLY

    lcx_kernel<<<grid, BLOCK, 0, stream>>>(xyz, sm, mask, out);
}

// Round 9
// 206.203 us; speedup vs baseline: 1.2403x; 1.0383x over previous
//
#include <hip/hip_runtime.h>
#include <hip/hip_fp16.h>

// out[n,c,h,w] = sum_{5x5 in-bounds taps} exp(-0.5*||xyz_nbr - xyz_ctr||^2)
//                * mask_nbr * softmax[n,c,nbr]
// OOB taps have weight forced to 0, so staged/loaded slots at clamped
// addresses may hold garbage; they are always multiplied by 0.0f.
//
// R13 = R12 (105us, first win: LDS-fed FMAs) with its three measured caps
// removed:
//  1) occupancy: LDS 78.8KB -> 2 blocks/CU. Fix: fp16 LDS. sm_s 23KB +
//     w_h 12.8KB = 35.8KB -> 4 blocks/CU (16 waves = the VGPR cap). RNE
//     cvt, values in [0,1]: added err ~<=0.01 vs 0.0156 baseline; R9/R11
//     passed at 0.03125. Accum stays fp32.
//  2) bank conflicts 1.376e7 (~22us): R12's f2 reads hit odd banks only.
//     Fix: ALL phase-2 reads are aligned b64 (3xb64 sm window covering
//     halfs cb..cb+11, 5xb64 weights): every pattern lands uniform
//     4 dwords/bank = the wave64-b64 minimum -> ~0 extra cycles.
//  3) serial phases: drop xyz_s (R10: staging xyz bought ~3us) -> weights
//     from global, computed in parallel with sm staging; ONE barrier.
// Edge blocks (pc==0/31) take a block-uniform clamped-scalar weight path.
// Plain __launch_bounds__ (R6/R7: min-waves caps spill catastrophically).
// 1D grid ONLY (2D gridDim.y broke harness graph replay in R3).

#define H_DIM 64
#define W_DIM 2048
#define C_DIM 20
#define N_DIM 8
#define HW (H_DIM * W_DIM)
#define BLOCK 256
#define HT 4             // output h-rows per block
#define PX 64            // output pixels per block
#define RS 8             // staged rows = HT + 4
#define CS 72            // staged cols = PX + 8
#define NGX 18           // float4 groups per staged row

struct h4v { __half2 lo, hi; };   // 8B, one b64

__global__ __launch_bounds__(BLOCK) void lcx_kernel(
    const float* __restrict__ xyz,
    const float* __restrict__ sm,
    const int*  __restrict__ mask,
    float* __restrict__ out)
{
    __shared__ __half sm_s[C_DIM][RS][CS];   // 23.04 KB
    __shared__ __half w_h[HT][25][PX];       // 12.8 KB

    const int b  = blockIdx.x;               // 4096: 32 pxc x 16 htile x 8 n
    const int pc = b & 31;
    const int ht = (b >> 5) & 15;
    const int n  = b >> 9;
    const int w0 = pc << 6;
    const int h0 = ht << 2;
    const int t  = threadIdx.x;

    const float* xyzn  = xyz  + n * 3 * HW;
    const int*   maskn = mask + n * HW;
    const float* smn   = sm   + n * C_DIM * HW;
    float*       outn  = out  + n * C_DIM * HW;

    // ---- Phase S: stage sm halo -> fp16 LDS (2880 f4 jobs, indep loads) ----
    #pragma unroll
    for (int it = 0; it < 12; ++it) {
        const int j = t + (it << 8);
        if (j < C_DIM * RS * NGX) {
            const int grp = j % NGX;
            const int rem = j / NGX;         // c*8 + row
            const int row = rem & 7;
            const int c   = rem >> 3;
            const int hi  = h0 - 2 + row;
            const int hic = (hi < 0) ? 0 : (hi > H_DIM - 1 ? H_DIM - 1 : hi);
            int gc = w0 - 4 + (grp << 2);    // 4-aligned halo: clamped groups
            gc = (gc < 0) ? 0 : (gc > W_DIM - 4 ? W_DIM - 4 : gc); // are fully OOB
            const float4 v = *(const float4*)(smn + c * HW + hic * W_DIM + gc);
            h4v p;
            p.lo = __floats2half2_rn(v.x, v.y);
            p.hi = __floats2half2_rn(v.z, v.w);
            *(h4v*)&sm_s[c][row][grp << 2] = p;
        }
    }

    // ---- Phase W: 25 weights for pixel (h0+whh, w0+wpl), from global ----
    {
        const int whh = t >> 6;              // wave-uniform h-row
        const int wpl = t & 63;
        const int px  = w0 + wpl;
        const int h   = h0 + whh;
        const int ctr = h * W_DIM + px;
        const float cx = xyzn[ctr];
        const float cy = xyzn[HW + ctr];
        const float cz = xyzn[2 * HW + ctr];
        const bool edgeblk = (pc == 0) || (pc == 31);  // block-uniform

        #pragma unroll
        for (int r = 0; r < 5; ++r) {
            const int hi = h + r - 2;
            float w5[5];
            if ((unsigned)hi >= (unsigned)H_DIM) {
                #pragma unroll
                for (int dj = 0; dj < 5; ++dj) w5[dj] = 0.0f;
            } else {
                const int rb = hi * W_DIM;
                if (!edgeblk) {
                    const int o = rb + px - 2;
                    const float4 xv = *(const float4*)(xyzn + o);
                    const float  xs = xyzn[o + 4];
                    const float4 yv = *(const float4*)(xyzn + HW + o);
                    const float  ys = xyzn[HW + o + 4];
                    const float4 zv = *(const float4*)(xyzn + 2 * HW + o);
                    const float  zs = xyzn[2 * HW + o + 4];
                    const int4   mv = *(const int4*)(maskn + o);
                    const int    ms = maskn[o + 4];
                    const float nx[5] = {xv.x, xv.y, xv.z, xv.w, xs};
                    const float ny[5] = {yv.x, yv.y, yv.z, yv.w, ys};
                    const float nz[5] = {zv.x, zv.y, zv.z, zv.w, zs};
                    const int   nm[5] = {mv.x, mv.y, mv.z, mv.w, ms};
                    #pragma unroll
                    for (int dj = 0; dj < 5; ++dj) {
                        const float dx = nx[dj] - cx;
                        const float dy = ny[dj] - cy;
                        const float dz = nz[dj] - cz;
                        const float d2 = fmaf(dx, dx, fmaf(dy, dy, dz * dz));
                        w5[dj] = (nm[dj] != 0) ? __expf(-0.5f * d2) : 0.0f;
                    }
                } else {
                    #pragma unroll
                    for (int dj = 0; dj < 5; ++dj) {
                        const int col = px + dj - 2;
                        const bool cok = ((unsigned)col < (unsigned)W_DIM);
                        const int cc  = cok ? col : (col < 0 ? 0 : W_DIM - 1);
                        const int o   = rb + cc;
                        const float dx = xyzn[o] - cx;
                        const float dy = xyzn[HW + o] - cy;
                        const float dz = xyzn[2 * HW + o] - cz;
                        const float d2 = fmaf(dx, dx, fmaf(dy, dy, dz * dz));
                        const bool ok = cok && (maskn[o] != 0);
                        w5[dj] = ok ? __expf(-0.5f * d2) : 0.0f;
                    }
                }
            }
            #pragma unroll
            for (int dj = 0; dj < 5; ++dj)
                w_h[whh][r * 5 + dj][wpl] = __float2half_rn(w5[dj]);
        }
    }
    __syncthreads();

    // ---- Phase 2: 4 px x 5 ch per thread, all-b64 LDS, fp32 accum ----
    const int cg = t >> 6;                   // channel group, wave-uniform
    const int hh = (t >> 4) & 3;             // h-row within tile
    const int pq = t & 15;                   // pixel quad
    const int cb = pq << 2;

    float4 acc[5];
    #pragma unroll
    for (int c = 0; c < 5; ++c) acc[c] = make_float4(0.f, 0.f, 0.f, 0.f);

    #pragma unroll
    for (int rt = 0; rt < 5; ++rt) {
        const int row = hh + rt;

        float4 wt[5];                        // 5 aligned b64, bank-uniform
        #pragma unroll
        for (int dj = 0; dj < 5; ++dj) {
            const h4v uw = *(const h4v*)&w_h[hh][rt * 5 + dj][cb];
            const float2 a = __half22float2(uw.lo);
            const float2 bq = __half22float2(uw.hi);
            wt[dj] = make_float4(a.x, a.y, bq.x, bq.y);
        }

        #pragma unroll
        for (int c = 0; c < 5; ++c) {
            const __half* base = &sm_s[cg * 5 + c][row][0];
            const h4v u0 = *(const h4v*)(base + cb);      // halfs cb..cb+3
            const h4v u1 = *(const h4v*)(base + cb + 4);  // cb+4..cb+7
            const h4v u2 = *(const h4v*)(base + cb + 8);  // cb+8..cb+11
            const float2 f01 = __half22float2(u0.hi);     // window 0,1
            const float2 f23 = __half22float2(u1.lo);     // window 2,3
            const float2 f45 = __half22float2(u1.hi);     // window 4,5
            const float2 f67 = __half22float2(u2.lo);     // window 6,7
            float fs[8];
            fs[0]=f01.x; fs[1]=f01.y; fs[2]=f23.x; fs[3]=f23.y;
            fs[4]=f45.x; fs[5]=f45.y; fs[6]=f67.x; fs[7]=f67.y;

            #pragma unroll
            for (int dj = 0; dj < 5; ++dj) {
                acc[c].x = fmaf(wt[dj].x, fs[0 + dj], acc[c].x);
                acc[c].y = fmaf(wt[dj].y, fs[1 + dj], acc[c].y);
                acc[c].z = fmaf(wt[dj].z, fs[2 + dj], acc[c].z);
                acc[c].w = fmaf(wt[dj].w, fs[3 + dj], acc[c].w);
            }
        }
    }

    const int ob = (h0 + hh) * W_DIM + w0 + cb;
    #pragma unroll
    for (int c = 0; c < 5; ++c)
        *(float4*)(outn + (cg * 5 + c) * HW + ob) = acc[c];
}

extern "C" void kernel_launch(void* const* d_in, const int* in_sizes, int n_in,
                              void* d_out, int out_size, void* d_ws, size_t ws_size,
                              hipStream_t stream)
{
    const float* xyz  = (const float*)d_in[0];
    const float* sm   = (const float*)d_in[1];
    const int*   mask = (const int*)d_in[2];
    float*       out  = (float*)d_out;

    const int grid = 32 * 16 * N_DIM;        // 4096 blocks, 1D ONLY

    lcx_kernel<<<grid, BLOCK, 0, stream>>>(xyz, sm, mask, out);
}